// Round 6
// baseline (682.501 us; speedup 1.0000x reference)
//
#include <hip/hip_runtime.h>

typedef unsigned short u16;
typedef unsigned int u32;
typedef unsigned long long u64;
typedef int   v4i  __attribute__((ext_vector_type(4)));
typedef short v8s  __attribute__((ext_vector_type(8)));
typedef float v2f  __attribute__((ext_vector_type(2)));
typedef float v16f __attribute__((ext_vector_type(16)));

#define B_ 256
#define T_ 120
#define E_ 256
#define H_ 1024
#define K_ 1280
#define LDH 1032    // 1024 + 8 pad (u16); row = 2064B, halves stay contiguous
#define LDX 264     // 256 + 8 pad

// ---- ws layout (bytes) ----
#define WS_WF   0                    // 10,485,760  (W fragments, bf16)
#define WS_X    10485760             // 15,728,640  (X (T,B,E) bf16)
#define WS_HS   26214400             // 62,914,560  (hs (T,B,H) bf16)
#define WS_BAR  89128960             // 4,096 (flags)

__device__ __forceinline__ u16 f2bf(float f) {
    union { float f; u32 u; } v; v.f = f;
    u32 r = v.u + 0x7fffu + ((v.u >> 16) & 1u);   // RNE
    return (u16)(r >> 16);
}
__device__ __forceinline__ float bf2f(u16 u) {
    union { u32 u; float f; } v; v.u = ((u32)u) << 16; return v.f;
}
__device__ __forceinline__ float fsig(float x) {
    float t = __builtin_amdgcn_exp2f(-1.44269504f * x);
    return __builtin_amdgcn_rcpf(1.0f + t);
}
__device__ __forceinline__ float ftanh_(float x) {
    float xc = fminf(8.0f, fmaxf(-8.0f, x));
    float t = __builtin_amdgcn_exp2f(2.88539008f * xc);
    return (t - 1.0f) * __builtin_amdgcn_rcpf(t + 1.0f);
}
__device__ __forceinline__ void gl_lds16(const void* g, void* l) {
    __builtin_amdgcn_global_load_lds(
        (const __attribute__((address_space(1))) void*)g,
        (__attribute__((address_space(3))) void*)l, 16, 0, 0);
}

// ---------------- P1+P2 fused: W repack + X gather + flag zeroing ----------------
// blocks [0,1280): W (1280,4096) f32 -> bf16 32x32x16 B-fragments (block 0 also
// zeroes the flag array). blocks [1280,5120): embedding gather -> X (T,B,E) bf16.
__global__ void prep_fused(const float* __restrict__ W, u16* __restrict__ Wf,
                           const int* __restrict__ tokens, const float* __restrict__ emb,
                           u16* __restrict__ X, u32* __restrict__ bar) {
    __shared__ u16 tile[32 * 136];        // [col 0..31][localk 0..127 + 8 pad]
    int bx  = blockIdx.x;
    int tid = threadIdx.x;

    if (bx < 1280) {
        // ---- prep_w ----
        if (bx == 0) {                     // zero flags (1024 u32 >= 8*T_)
            v4i z = {0, 0, 0, 0};
            *(v4i*)(bar + tid * 4) = z;
        }
        int cid = bx / 5, fo = bx % 5;
        int kh  = cid & 1, g = (cid >> 1) & 3, nc = cid >> 3;
        int colbase = g * 1024 + nc * 32;
        int c = tid & 31, r = tid >> 5;   // r 0..7

#pragma unroll
        for (int fl = 0; fl < 8; ++fl) {
            int k0 = (2 * (fo * 8 + fl) + kh) * 16;
#pragma unroll
            for (int rr = 0; rr < 2; ++rr) {
                int row = r + rr * 8;     // 0..15
                float v = W[(size_t)(k0 + row) * 4096 + colbase + c];
                tile[c * 136 + fl * 16 + row] = f2bf(v);
            }
        }
        __syncthreads();

        int lane = tid & 63;
#pragma unroll
        for (int pass = 0; pass < 2; ++pass) {
            int fl = (tid >> 6) + pass * 4;
            v4i o = *(const v4i*)&tile[(lane & 31) * 136 + fl * 16 + ((lane >> 5) << 3)];
            *(v4i*)(Wf + (((size_t)(cid * 40 + fo * 8 + fl)) << 9) + lane * 8) = o;
        }
    } else {
        // ---- prep_x ----
        int v   = (bx - 1280) * 256 + tid;            // < 983040
        int e8  = v & 31;
        int row = v >> 5;                             // t*256 + b
        int t = row >> 8, b = row & 255;
        int tok = tokens[b * T_ + t];
        const float* src = emb + (size_t)tok * E_ + e8 * 8;
        u16 o[8];
#pragma unroll
        for (int j = 0; j < 8; ++j) o[j] = f2bf(src[j]);
        *(v4i*)(X + (size_t)row * E_ + e8 * 8) = *(v4i*)o;
    }
}

// ---------------- main persistent LSTM kernel (+ folded projection) ----------------
// 256 blocks x 512 threads. Block (mchunk=bid&7, nc=bid>>3). Wave (g=wv>>1,
// khalf=wv&1): 32x32 gate tile, K-parity split. W pinned in registers.
// h staged async via global_load_lds in 2 pipelined 512-col chunks with raw
// s_waitcnt vmcnt(N)+s_barrier; x-part MFMAs for t+1 hide the flag handshake.
// Exchange protocol == proven 509us baseline (agent scope, rounds 0-4 axis
// reverted: XCD-local variants were neutral-to-negative).
//
// FOLDED PROJ: during step t (t>=1) hbuf holds full h(t-1) rows m0..m0+31.
// Each block projects ONE row (its nc-th): 512 thr x 2 cols x 5 classes,
// per-wave shfl reduce -> pscr, merged across waves through the existing
// gates __syncthreads; threads 0..4 write out[(m0+nc), t-1, :]. Epilogue
// runs one extra exchange for h(119). Removes the separate proj kernel.
__global__ __launch_bounds__(512, 2) void lstm_main(
    const u16* __restrict__ Wf, const u16* __restrict__ X,
    const float* __restrict__ b_lstm, u16* __restrict__ hs,
    u32* __restrict__ bar, const float* __restrict__ U,
    const float* __restrict__ b2, float* __restrict__ out) {

    __shared__ u16  hbuf[32 * LDH];          // 66,048 B
    __shared__ u16  xbuf[32 * LDX];          // 16,896 B
    __shared__ float gates[2 * 4 * 32 * 34]; // 34,816 B
    __shared__ float bias[128];
    __shared__ float Ul[H_ * 5];             // 20,480 B
    __shared__ float b2l[5];
    __shared__ float pscr[40];               // 8 waves x 5 classes

    const int tid   = threadIdx.x;
    const int lane  = tid & 63;
    const int wv    = tid >> 6;
    const int g     = wv >> 1;
    const int khalf = wv & 1;
    const int bid   = blockIdx.x;
    const int mchunk = bid & 7;
    const int nc    = bid >> 3;
    const int m0    = mchunk << 5;

    if (tid < 128) bias[tid] = b_lstm[(tid >> 5) * H_ + (nc << 5) + (tid & 31)];
    for (int i = tid; i < H_ * 5; i += 512) Ul[i] = U[i];
    if (tid < 5) b2l[tid] = b2[tid];

    // ---- resident W fragments: 40 x v8s, pinned ----
    v8s Wr[40];
    {
        const int cid = nc * 8 + g * 2 + khalf;
        const v4i* wsrc = (const v4i*)(Wf + (size_t)cid * 40 * 512);
#pragma unroll
        for (int f = 0; f < 40; ++f)
            Wr[f] = __builtin_bit_cast(v8s, wsrc[f * 64 + lane]);
    }
#pragma unroll
    for (int f = 0; f < 40; ++f) asm volatile("" : "+v"(Wr[f]));

    // ---- stage X_0 ----
    {
        const v4i* xs = (const v4i*)(X + (size_t)m0 * E_);
#pragma unroll
        for (int i = 0; i < 2; ++i) {
            int idx = tid + i * 512;
            int r = idx >> 5, c8 = idx & 31;
            *(v4i*)&xbuf[r * LDX + c8 * 8] = xs[r * 32 + c8];
        }
    }
    __syncthreads();

    const u16* Ax = &xbuf[(lane & 31) * LDX + ((lane >> 5) << 3)];
    const u16* Ah = &hbuf[(lane & 31) * LDH + ((lane >> 5) << 3)];

    // ---- x-part MFMA for t=0 ----
    v16f acc = {0,0,0,0,0,0,0,0,0,0,0,0,0,0,0,0};
#pragma unroll
    for (int f = 0; f < 8; ++f) {
        v8s a = *(const v8s*)(Ax + (2 * f + khalf) * 16);
        acc = __builtin_amdgcn_mfma_f32_32x32x16_bf16(a, Wr[f], acc, 0, 0, 0);
    }

    float cst[2] = {0.f, 0.f};
    const int cm  = tid >> 4;
    const int cn2 = (tid & 15) << 1;
    u32* hs32 = (u32*)hs;

    for (int t = 0; t < T_; ++t) {
        if (t > 0) {
            // ---- wait for h_{t-1} flag (usually already set: hidden by x-MFMAs) ----
            if (tid == 0) {
                u32* p = &bar[mchunk * T_ + (t - 1)];
                while (__hip_atomic_load(p, __ATOMIC_RELAXED, __HIP_MEMORY_SCOPE_AGENT) < 32u)
                    __builtin_amdgcn_s_sleep(1);
            }
            __syncthreads();
            // ---- issue async h loads: wave wv -> rows [wv*4, wv*4+4), halves 0,1 ----
            {
                const u16* srcb = hs + ((size_t)(t - 1) * B_ + m0) * H_;
                int r0 = wv << 2;
#pragma unroll
                for (int half = 0; half < 2; ++half)
#pragma unroll
                    for (int i = 0; i < 4; ++i) {
                        int r = r0 + i;
                        gl_lds16(srcb + (size_t)r * H_ + half * 512 + lane * 8,
                                 &hbuf[r * LDH + half * 512]);
                    }
            }
            // ---- chunk A: cols [0,512) ready after own-wave vmcnt(4) + barrier ----
            asm volatile("s_waitcnt vmcnt(4)\n\ts_barrier" ::: "memory");
#pragma unroll
            for (int f = 8; f < 24; ++f) {
                v8s a = *(const v8s*)(Ah + ((2 * f + khalf) * 16 - 256));
                acc = __builtin_amdgcn_mfma_f32_32x32x16_bf16(a, Wr[f], acc, 0, 0, 0);
            }
            // ---- chunk B: cols [512,1024) ----
            asm volatile("s_waitcnt vmcnt(0)\n\ts_barrier" ::: "memory");
#pragma unroll
            for (int f = 24; f < 40; ++f) {
                v8s a = *(const v8s*)(Ah + ((2 * f + khalf) * 16 - 256));
                acc = __builtin_amdgcn_mfma_f32_32x32x16_bf16(a, Wr[f], acc, 0, 0, 0);
            }

            // ---- folded proj partials for h(t-1), row nc of hbuf ----
            {
                u32 hv = *(const u32*)&hbuf[nc * LDH + (tid << 1)];
                float h0 = bf2f((u16)(hv & 0xffffu));
                float h1 = bf2f((u16)(hv >> 16));
                int k = tid << 1;
                float pp[5];
#pragma unroll
                for (int c = 0; c < 5; ++c)
                    pp[c] = h0 * Ul[k * 5 + c] + h1 * Ul[(k + 1) * 5 + c];
#pragma unroll
                for (int c = 0; c < 5; ++c)
#pragma unroll
                    for (int off = 32; off > 0; off >>= 1)
                        pp[c] += __shfl_down(pp[c], off, 64);
                if (lane == 0) {
#pragma unroll
                    for (int c = 0; c < 5; ++c) pscr[wv * 5 + c] = pp[c];
                }
            }
        }

        // ---- partials -> LDS: C/D col=lane&31, row=(reg&3)+8*(reg>>2)+4*(lane>>5) ----
        {
            float* gb = &gates[((khalf << 2) + g) * 1088];
            int col = lane & 31, rq = (lane >> 5) << 2;
#pragma unroll
            for (int reg = 0; reg < 16; ++reg) {
                int row = (reg & 3) + ((reg >> 2) << 3) + rq;
                gb[row * 34 + col] = acc[reg];
            }
        }
        __syncthreads();

        // ---- finish folded proj: merge 8 wave partials, write out[(m0+nc), t-1] ----
        if (t > 0 && tid < 5) {
            float s = 0.f;
#pragma unroll
            for (int w = 0; w < 8; ++w) s += pscr[w * 5 + tid];
            out[((size_t)(m0 + nc) * T_ + (t - 1)) * 5 + tid] = s + b2l[tid];
        }

        // ---- prefetch X_{t+1} (issues early; overlaps cell transcendentals) ----
        if (t + 1 < T_) {
            const v4i* xs = (const v4i*)(X + ((size_t)(t + 1) * B_ + m0) * E_);
#pragma unroll
            for (int i = 0; i < 2; ++i) {
                int idx = tid + i * 512;
                int r = idx >> 5, c8 = idx & 31;
                *(v4i*)&xbuf[r * LDX + c8 * 8] = xs[r * 32 + c8];
            }
        }

        // ---- cell math: sum K-halves, bias, activations ----
        u32 hpack = 0;
        {
            v2f zz[4];
#pragma unroll
            for (int gg = 0; gg < 4; ++gg) {
                v2f a = *(const v2f*)&gates[gg * 1088 + cm * 34 + cn2];
                v2f b = *(const v2f*)&gates[(4 + gg) * 1088 + cm * 34 + cn2];
                zz[gg].x = a.x + b.x; zz[gg].y = a.y + b.y;
            }
#pragma unroll
            for (int q = 0; q < 2; ++q) {
                int n = cn2 + q;
                float ip = zz[0][q] + bias[n];
                float jp = zz[1][q] + bias[32 + n];
                float fp = zz[2][q] + bias[64 + n] + 1.0f;
                float op = zz[3][q] + bias[96 + n];
                float cc = fsig(fp) * cst[q] + fsig(ip) * ftanh_(jp);
                cst[q] = cc;
                hpack |= ((u32)f2bf(fsig(op) * ftanh_(cc))) << (16 * q);
            }
        }
        __hip_atomic_store(&hs32[((size_t)t * B_ + m0 + cm) * 512 + (nc << 4) + (tid & 15)],
                           hpack, __ATOMIC_RELAXED, __HIP_MEMORY_SCOPE_AGENT);

        if (t + 1 < T_) {
            // ---- release: each wave drains its own VM ops, barrier, then flag ----
            asm volatile("s_waitcnt vmcnt(0)" ::: "memory");
            __syncthreads();
            if (tid == 0)
                __hip_atomic_fetch_add(&bar[mchunk * T_ + t], 1u,
                                       __ATOMIC_RELAXED, __HIP_MEMORY_SCOPE_AGENT);
            // ---- x-part MFMA for t+1 (hides handshake latency) ----
#pragma unroll
            for (int reg = 0; reg < 16; ++reg) acc[reg] = 0.f;
#pragma unroll
            for (int f = 0; f < 8; ++f) {
                v8s a = *(const v8s*)(Ax + (2 * f + khalf) * 16);
                acc = __builtin_amdgcn_mfma_f32_32x32x16_bf16(a, Wr[f], acc, 0, 0, 0);
            }
        }
    }

    // ---- epilogue: one more exchange to project h(119) ----
    asm volatile("s_waitcnt vmcnt(0)" ::: "memory");
    __syncthreads();
    if (tid == 0) {
        __hip_atomic_fetch_add(&bar[mchunk * T_ + (T_ - 1)], 1u,
                               __ATOMIC_RELAXED, __HIP_MEMORY_SCOPE_AGENT);
        u32* p = &bar[mchunk * T_ + (T_ - 1)];
        while (__hip_atomic_load(p, __ATOMIC_RELAXED, __HIP_MEMORY_SCOPE_AGENT) < 32u)
            __builtin_amdgcn_s_sleep(1);
    }
    __syncthreads();
    {
        const u16* srcb = hs + ((size_t)(T_ - 1) * B_ + m0) * H_;
        int r0 = wv << 2;
#pragma unroll
        for (int half = 0; half < 2; ++half)
#pragma unroll
            for (int i = 0; i < 4; ++i) {
                int r = r0 + i;
                gl_lds16(srcb + (size_t)r * H_ + half * 512 + lane * 8,
                         &hbuf[r * LDH + half * 512]);
            }
    }
    asm volatile("s_waitcnt vmcnt(0)\n\ts_barrier" ::: "memory");
    {
        u32 hv = *(const u32*)&hbuf[nc * LDH + (tid << 1)];
        float h0 = bf2f((u16)(hv & 0xffffu));
        float h1 = bf2f((u16)(hv >> 16));
        int k = tid << 1;
        float pp[5];
#pragma unroll
        for (int c = 0; c < 5; ++c)
            pp[c] = h0 * Ul[k * 5 + c] + h1 * Ul[(k + 1) * 5 + c];
#pragma unroll
        for (int c = 0; c < 5; ++c)
#pragma unroll
            for (int off = 32; off > 0; off >>= 1)
                pp[c] += __shfl_down(pp[c], off, 64);
        if (lane == 0) {
#pragma unroll
            for (int c = 0; c < 5; ++c) pscr[wv * 5 + c] = pp[c];
        }
    }
    __syncthreads();
    if (tid < 5) {
        float s = 0.f;
#pragma unroll
        for (int w = 0; w < 8; ++w) s += pscr[w * 5 + tid];
        out[((size_t)(m0 + nc) * T_ + (T_ - 1)) * 5 + tid] = s + b2l[tid];
    }
}

extern "C" void kernel_launch(void* const* d_in, const int* in_sizes, int n_in,
                              void* d_out, int out_size, void* d_ws, size_t ws_size,
                              hipStream_t stream) {
    const int*   tokens = (const int*)d_in[0];
    const float* emb    = (const float*)d_in[1];
    const float* W      = (const float*)d_in[2];
    const float* b_l    = (const float*)d_in[3];
    const float* U      = (const float*)d_in[4];
    const float* b2     = (const float*)d_in[5];
    float* out = (float*)d_out;

    char* ws = (char*)d_ws;
    u16* Wf  = (u16*)(ws + WS_WF);
    u16* X   = (u16*)(ws + WS_X);
    u16* hs  = (u16*)(ws + WS_HS);
    u32* bar = (u32*)(ws + WS_BAR);

    prep_fused<<<5120, 256, 0, stream>>>(W, Wf, tokens, emb, X, bar);
    lstm_main<<<256, 512, 0, stream>>>(Wf, X, b_l, hs, bar, U, b2, out);
}

// Round 7
// 580.597 us; speedup vs baseline: 1.1755x; 1.1755x over previous
//
#include <hip/hip_runtime.h>

typedef unsigned short u16;
typedef unsigned int u32;
typedef unsigned long long u64;
typedef int   v4i  __attribute__((ext_vector_type(4)));
typedef short v8s  __attribute__((ext_vector_type(8)));
typedef float v2f  __attribute__((ext_vector_type(2)));
typedef float v16f __attribute__((ext_vector_type(16)));

#define B_ 256
#define T_ 120
#define E_ 256
#define H_ 1024
#define K_ 1280
#define LDH 1032    // 1024 + 8 pad (u16); row = 2064B, halves stay contiguous
#define LDX 264     // 256 + 8 pad

// ---- ws layout (bytes) ----
#define WS_WF   0                    // 10,485,760  (W fragments, bf16)
#define WS_X    10485760             // 15,728,640  (X (T,B,E) bf16)
#define WS_HS   26214400             // 62,914,560  (hs (T,B,H) bf16)
#define WS_BAR  89128960             // 4,096 (per-producer counters, 16B spacing)

__device__ __forceinline__ u16 f2bf(float f) {
    union { float f; u32 u; } v; v.f = f;
    u32 r = v.u + 0x7fffu + ((v.u >> 16) & 1u);   // RNE
    return (u16)(r >> 16);
}
__device__ __forceinline__ float bf2f(u16 u) {
    union { u32 u; float f; } v; v.u = ((u32)u) << 16; return v.f;
}
__device__ __forceinline__ float fsig(float x) {
    float t = __builtin_amdgcn_exp2f(-1.44269504f * x);
    return __builtin_amdgcn_rcpf(1.0f + t);
}
__device__ __forceinline__ float ftanh_(float x) {
    float xc = fminf(8.0f, fmaxf(-8.0f, x));
    float t = __builtin_amdgcn_exp2f(2.88539008f * xc);
    return (t - 1.0f) * __builtin_amdgcn_rcpf(t + 1.0f);
}
__device__ __forceinline__ void gl_lds16(const void* g, void* l) {
    __builtin_amdgcn_global_load_lds(
        (const __attribute__((address_space(1))) void*)g,
        (__attribute__((address_space(3))) void*)l, 16, 0, 0);
}

// ---------------- P1+P2 fused: W repack + X gather + flag zeroing ----------------
// blocks [0,1280): W (1280,4096) f32 -> bf16 32x32x16 B-fragments (block 0 also
// zeroes the 4KB flag region). blocks [1280,5120): embedding gather -> X bf16.
__global__ void prep_fused(const float* __restrict__ W, u16* __restrict__ Wf,
                           const int* __restrict__ tokens, const float* __restrict__ emb,
                           u16* __restrict__ X, u32* __restrict__ bar) {
    __shared__ u16 tile[32 * 136];        // [col 0..31][localk 0..127 + 8 pad]
    int bx  = blockIdx.x;
    int tid = threadIdx.x;

    if (bx < 1280) {
        // ---- prep_w ----
        if (bx == 0) {                     // zero per-producer counters (1024 u32)
            v4i z = {0, 0, 0, 0};
            *(v4i*)(bar + tid * 4) = z;
        }
        int cid = bx / 5, fo = bx % 5;
        int kh  = cid & 1, g = (cid >> 1) & 3, nc = cid >> 3;
        int colbase = g * 1024 + nc * 32;
        int c = tid & 31, r = tid >> 5;   // r 0..7

#pragma unroll
        for (int fl = 0; fl < 8; ++fl) {
            int k0 = (2 * (fo * 8 + fl) + kh) * 16;
#pragma unroll
            for (int rr = 0; rr < 2; ++rr) {
                int row = r + rr * 8;     // 0..15
                float v = W[(size_t)(k0 + row) * 4096 + colbase + c];
                tile[c * 136 + fl * 16 + row] = f2bf(v);
            }
        }
        __syncthreads();

        int lane = tid & 63;
#pragma unroll
        for (int pass = 0; pass < 2; ++pass) {
            int fl = (tid >> 6) + pass * 4;
            v4i o = *(const v4i*)&tile[(lane & 31) * 136 + fl * 16 + ((lane >> 5) << 3)];
            *(v4i*)(Wf + (((size_t)(cid * 40 + fo * 8 + fl)) << 9) + lane * 8) = o;
        }
    } else {
        // ---- prep_x ----
        int v   = (bx - 1280) * 256 + tid;            // < 983040
        int e8  = v & 31;
        int row = v >> 5;                             // t*256 + b
        int t = row >> 8, b = row & 255;
        int tok = tokens[b * T_ + t];
        const float* src = emb + (size_t)tok * E_ + e8 * 8;
        u16 o[8];
#pragma unroll
        for (int j = 0; j < 8; ++j) o[j] = f2bf(src[j]);
        *(v4i*)(X + (size_t)row * E_ + e8 * 8) = *(v4i*)o;
    }
}

// ---------------- main persistent LSTM kernel ----------------
// 256 blocks x 512 threads. Block (mchunk=bid&7, nc=bid>>3). Wave (g=wv>>1,
// khalf=wv&1): 32x32 gate tile, K-parity split. W pinned in registers.
// h staged async via global_load_lds in 2 pipelined 512-col chunks with raw
// s_waitcnt vmcnt(N)+s_barrier; x-part MFMAs for t+1 hide the flag handshake.
// Round-6 folded proj REVERTED (it inserted a 6-deep shfl-reduce into the
// inter-block serial chain: +113us measured). Body == proven 509us baseline
// except the flag mechanism:
//
// FLAG CHANGE (round 7's single variable): instead of 32 producers doing
// fetch_add on ONE word per (mchunk,t) — 32 RMWs convoying on a single IC
// line every step — each producer owns a private counter word (16B spacing,
// monotonic "last completed step + 1", stored once per step after the h
// drain). The consumer polls all 32 counters in parallel with wave-0's
// lanes and __all(v >= t). Same ordering guarantees, no RMW serialization.
__global__ __launch_bounds__(512, 2) void lstm_main(
    const u16* __restrict__ Wf, const u16* __restrict__ X,
    const float* __restrict__ b_lstm, u16* __restrict__ hs,
    u32* __restrict__ bar) {

    __shared__ u16  hbuf[32 * LDH];          // 66,048 B
    __shared__ u16  xbuf[32 * LDX];          // 16,896 B
    __shared__ float gates[2 * 4 * 32 * 34]; // 34,816 B
    __shared__ float bias[128];

    const int tid   = threadIdx.x;
    const int lane  = tid & 63;
    const int wv    = tid >> 6;
    const int g     = wv >> 1;
    const int khalf = wv & 1;
    const int bid   = blockIdx.x;
    const int mchunk = bid & 7;
    const int nc    = bid >> 3;
    const int m0    = mchunk << 5;

    if (tid < 128) bias[tid] = b_lstm[(tid >> 5) * H_ + (nc << 5) + (tid & 31)];

    // ---- resident W fragments: 40 x v8s, pinned ----
    v8s Wr[40];
    {
        const int cid = nc * 8 + g * 2 + khalf;
        const v4i* wsrc = (const v4i*)(Wf + (size_t)cid * 40 * 512);
#pragma unroll
        for (int f = 0; f < 40; ++f)
            Wr[f] = __builtin_bit_cast(v8s, wsrc[f * 64 + lane]);
    }
#pragma unroll
    for (int f = 0; f < 40; ++f) asm volatile("" : "+v"(Wr[f]));

    // ---- stage X_0 ----
    {
        const v4i* xs = (const v4i*)(X + (size_t)m0 * E_);
#pragma unroll
        for (int i = 0; i < 2; ++i) {
            int idx = tid + i * 512;
            int r = idx >> 5, c8 = idx & 31;
            *(v4i*)&xbuf[r * LDX + c8 * 8] = xs[r * 32 + c8];
        }
    }
    __syncthreads();

    const u16* Ax = &xbuf[(lane & 31) * LDX + ((lane >> 5) << 3)];
    const u16* Ah = &hbuf[(lane & 31) * LDH + ((lane >> 5) << 3)];

    // ---- x-part MFMA for t=0 ----
    v16f acc = {0,0,0,0,0,0,0,0,0,0,0,0,0,0,0,0};
#pragma unroll
    for (int f = 0; f < 8; ++f) {
        v8s a = *(const v8s*)(Ax + (2 * f + khalf) * 16);
        acc = __builtin_amdgcn_mfma_f32_32x32x16_bf16(a, Wr[f], acc, 0, 0, 0);
    }

    float cst[2] = {0.f, 0.f};
    const int cm  = tid >> 4;
    const int cn2 = (tid & 15) << 1;
    u32* hs32 = (u32*)hs;

    for (int t = 0; t < T_; ++t) {
        if (t > 0) {
            // ---- wait for h_{t-1}: wave 0 polls the 32 producer counters ----
            if (wv == 0) {
                u32* p = &bar[(mchunk * 32 + (lane & 31)) * 4];
                for (;;) {
                    u32 v = __hip_atomic_load(p, __ATOMIC_RELAXED,
                                              __HIP_MEMORY_SCOPE_AGENT);
                    if (__all(v >= (u32)t)) break;
                    __builtin_amdgcn_s_sleep(1);
                }
            }
            __syncthreads();
            // ---- issue async h loads: wave wv -> rows [wv*4, wv*4+4), halves 0,1 ----
            {
                const u16* srcb = hs + ((size_t)(t - 1) * B_ + m0) * H_;
                int r0 = wv << 2;
#pragma unroll
                for (int half = 0; half < 2; ++half)
#pragma unroll
                    for (int i = 0; i < 4; ++i) {
                        int r = r0 + i;
                        gl_lds16(srcb + (size_t)r * H_ + half * 512 + lane * 8,
                                 &hbuf[r * LDH + half * 512]);
                    }
            }
            // ---- chunk A: cols [0,512) ready after own-wave vmcnt(4) + barrier ----
            asm volatile("s_waitcnt vmcnt(4)\n\ts_barrier" ::: "memory");
#pragma unroll
            for (int f = 8; f < 24; ++f) {
                v8s a = *(const v8s*)(Ah + ((2 * f + khalf) * 16 - 256));
                acc = __builtin_amdgcn_mfma_f32_32x32x16_bf16(a, Wr[f], acc, 0, 0, 0);
            }
            // ---- chunk B: cols [512,1024) ----
            asm volatile("s_waitcnt vmcnt(0)\n\ts_barrier" ::: "memory");
#pragma unroll
            for (int f = 24; f < 40; ++f) {
                v8s a = *(const v8s*)(Ah + ((2 * f + khalf) * 16 - 256));
                acc = __builtin_amdgcn_mfma_f32_32x32x16_bf16(a, Wr[f], acc, 0, 0, 0);
            }
        }

        // ---- partials -> LDS: C/D col=lane&31, row=(reg&3)+8*(reg>>2)+4*(lane>>5) ----
        {
            float* gb = &gates[((khalf << 2) + g) * 1088];
            int col = lane & 31, rq = (lane >> 5) << 2;
#pragma unroll
            for (int reg = 0; reg < 16; ++reg) {
                int row = (reg & 3) + ((reg >> 2) << 3) + rq;
                gb[row * 34 + col] = acc[reg];
            }
        }
        __syncthreads();

        // ---- prefetch X_{t+1} (issues early; overlaps cell transcendentals) ----
        if (t + 1 < T_) {
            const v4i* xs = (const v4i*)(X + ((size_t)(t + 1) * B_ + m0) * E_);
#pragma unroll
            for (int i = 0; i < 2; ++i) {
                int idx = tid + i * 512;
                int r = idx >> 5, c8 = idx & 31;
                *(v4i*)&xbuf[r * LDX + c8 * 8] = xs[r * 32 + c8];
            }
        }

        // ---- cell math: sum K-halves, bias, activations ----
        u32 hpack = 0;
        {
            v2f zz[4];
#pragma unroll
            for (int gg = 0; gg < 4; ++gg) {
                v2f a = *(const v2f*)&gates[gg * 1088 + cm * 34 + cn2];
                v2f b = *(const v2f*)&gates[(4 + gg) * 1088 + cm * 34 + cn2];
                zz[gg].x = a.x + b.x; zz[gg].y = a.y + b.y;
            }
#pragma unroll
            for (int q = 0; q < 2; ++q) {
                int n = cn2 + q;
                float ip = zz[0][q] + bias[n];
                float jp = zz[1][q] + bias[32 + n];
                float fp = zz[2][q] + bias[64 + n] + 1.0f;
                float op = zz[3][q] + bias[96 + n];
                float cc = fsig(fp) * cst[q] + fsig(ip) * ftanh_(jp);
                cst[q] = cc;
                hpack |= ((u32)f2bf(fsig(op) * ftanh_(cc))) << (16 * q);
            }
        }
        __hip_atomic_store(&hs32[((size_t)t * B_ + m0 + cm) * 512 + (nc << 4) + (tid & 15)],
                           hpack, __ATOMIC_RELAXED, __HIP_MEMORY_SCOPE_AGENT);

        if (t + 1 < T_) {
            // ---- release: drain own VM ops, barrier, then own counter = t+1 ----
            asm volatile("s_waitcnt vmcnt(0)" ::: "memory");
            __syncthreads();
            if (tid == 0)
                __hip_atomic_store(&bar[(mchunk * 32 + nc) * 4], (u32)(t + 1),
                                   __ATOMIC_RELAXED, __HIP_MEMORY_SCOPE_AGENT);
            // ---- x-part MFMA for t+1 (hides handshake latency) ----
#pragma unroll
            for (int reg = 0; reg < 16; ++reg) acc[reg] = 0.f;
#pragma unroll
            for (int f = 0; f < 8; ++f) {
                v8s a = *(const v8s*)(Ax + (2 * f + khalf) * 16);
                acc = __builtin_amdgcn_mfma_f32_32x32x16_bf16(a, Wr[f], acc, 0, 0, 0);
            }
        }
    }
}

// ---------------- P3: preds = hs @ U + b2 (64 rows/block; U staged once) ----------------
__global__ void proj_kernel(const u16* __restrict__ hs, const float* __restrict__ U,
                            const float* __restrict__ b2, float* __restrict__ out) {
    __shared__ float Ul[H_ * 5];
    int tid = threadIdx.x;
    for (int i = tid; i < H_ * 5; i += 256) Ul[i] = U[i];
    __syncthreads();
    int wv = tid >> 6, lane = tid & 63;
#pragma unroll 1
    for (int i = 0; i < 16; ++i) {
        int row = blockIdx.x * 64 + wv * 16 + i;   // t*256 + b, < 30720
        int t = row >> 8, b = row & 255;
        const v4i* hp = (const v4i*)(hs + (size_t)row * H_);
        float p[5] = {0.f, 0.f, 0.f, 0.f, 0.f};
#pragma unroll
        for (int half = 0; half < 2; ++half) {
            v4i hv = hp[lane * 2 + half];
            u16 us[8];
            *(v4i*)us = hv;
#pragma unroll
            for (int j = 0; j < 8; ++j) {
                float hf = bf2f(us[j]);
                int k = lane * 16 + half * 8 + j;
#pragma unroll
                for (int c = 0; c < 5; ++c) p[c] += hf * Ul[k * 5 + c];
            }
        }
#pragma unroll
        for (int c = 0; c < 5; ++c)
            for (int off = 32; off > 0; off >>= 1)
                p[c] += __shfl_down(p[c], off, 64);
        if (lane == 0) {
#pragma unroll
            for (int c = 0; c < 5; ++c)
                out[((size_t)b * T_ + t) * 5 + c] = p[c] + b2[c];
        }
    }
}

extern "C" void kernel_launch(void* const* d_in, const int* in_sizes, int n_in,
                              void* d_out, int out_size, void* d_ws, size_t ws_size,
                              hipStream_t stream) {
    const int*   tokens = (const int*)d_in[0];
    const float* emb    = (const float*)d_in[1];
    const float* W      = (const float*)d_in[2];
    const float* b_l    = (const float*)d_in[3];
    const float* U      = (const float*)d_in[4];
    const float* b2     = (const float*)d_in[5];
    float* out = (float*)d_out;

    char* ws = (char*)d_ws;
    u16* Wf  = (u16*)(ws + WS_WF);
    u16* X   = (u16*)(ws + WS_X);
    u16* hs  = (u16*)(ws + WS_HS);
    u32* bar = (u32*)(ws + WS_BAR);

    prep_fused<<<5120, 256, 0, stream>>>(W, Wf, tokens, emb, X, bar);
    lstm_main<<<256, 512, 0, stream>>>(Wf, X, b_l, hs, bar);
    proj_kernel<<<480, 256, 0, stream>>>(hs, U, b2, out);
}